// Round 6
// baseline (231.804 us; speedup 1.0000x reference)
//
#include <hip/hip_runtime.h>

#define N 8192
#define NCLS 81
#define PAD 300
#define NPANEL 16
#define PANW 512
#define JSPLIT 8

typedef unsigned long long u64;

// ---------------- K1: decode + argmax pick + key pack + rank zero ----------------
__global__ __launch_bounds__(64) void decode_kernel(
    const float* __restrict__ meta, const float* __restrict__ deltas,
    const float* __restrict__ proposals, const float* __restrict__ scores,
    float4* __restrict__ sel, u64* __restrict__ keys, int* __restrict__ rank) {
  int row = blockIdx.x * 64 + threadIdx.x;
  if (row >= N) return;
  float H = meta[0], W = meta[1], sc = meta[2];
  const float* p = proposals + row * 4;
  float x1 = p[0] / sc, y1 = p[1] / sc, x2 = p[2] / sc, y2 = p[3] / sc;
  float w = x2 - x1 + 1.0f, h = y2 - y1 + 1.0f;
  float cx = x1 + 0.5f * w, cy = y1 + 0.5f * h;

  const float* s = scores + (size_t)row * NCLS;
  int best = 0;
  float bs = s[0];
  float ms = -1e30f;  // max over classes 1..80
  for (int c = 1; c < NCLS; ++c) {
    float v = s[c];
    if (v > bs) { bs = v; best = c; }  // strict > : first-max, matches jnp.argmax
    ms = fmaxf(ms, v);
  }

  const float* d = deltas + (size_t)row * (4 * NCLS) + best * 4;
  float pcx = d[0] * w + cx;
  float pcy = d[1] * h + cy;
  float pw = expf(d[2]) * w;
  float ph = expf(d[3]) * h;
  float lx = W - 1.0f, ly = H - 1.0f;
  float ox1 = fminf(fmaxf(pcx - 0.5f * pw, 0.0f), lx);
  float oy1 = fminf(fmaxf(pcy - 0.5f * ph, 0.0f), ly);
  float ox2 = fminf(fmaxf(pcx + 0.5f * pw, 0.0f), lx);
  float oy2 = fminf(fmaxf(pcy + 0.5f * ph, 0.0f), ly);
  sel[row] = make_float4(ox1, oy1, ox2, oy2);
  keys[row] = ((u64)(~__float_as_uint(ms)) << 32) | (unsigned int)row;
  rank[row] = 0;
}

// ---------------- K2a: brute-force rank (stable sort of unique keys) ----------------
__global__ __launch_bounds__(256) void rank_kernel(
    const u64* __restrict__ keys, int* __restrict__ rank) {
  int i = blockIdx.x * 256 + threadIdx.x;
  u64 ki = keys[i];
  int j0 = blockIdx.y * (N / JSPLIT);
  int c = 0;
#pragma unroll 8
  for (int j = j0; j < j0 + N / JSPLIT; ++j) c += (keys[j] < ki);
  atomicAdd(&rank[i], c);
}

// ---------------- K2b: scatter into sorted order ----------------
__global__ __launch_bounds__(256) void scatter_kernel(
    const int* __restrict__ rank, const float4* __restrict__ sel,
    int* __restrict__ sortedIdx, float4* __restrict__ sortedBoxes) {
  int i = blockIdx.x * 256 + threadIdx.x;
  int r = rank[i];
  sortedIdx[r] = i;
  sortedBoxes[r] = sel[i];
}

// ---------------- K3: suppression bitmask, ROW-MAJOR, upper triangle only ------
// mask[r*128 + cb] bit c set iff j = cb*64+c, j > r, IoU > 0.5.
// Lower-tri block words (cb < r>>6) left as poison — consumers provably never use
// them (scan reads only diagonal-block words via slab; fold poison lands at
// col-blocks <= 8p+7, future panels read only col-blocks >= 8p+8).
// Division eliminated bit-exactly: RN(a/u) > 0.5  <=>  a*2^25 - u*2^24 - u > 0
// (muls are exact power-of-2 scalings; Sterbenz => exact subtraction near the
// threshold; sign robust elsewhere; tie/zero cases agree with IEEE div).
__global__ __launch_bounds__(64) void mask_kernel(
    const float4* __restrict__ boxes, u64* __restrict__ mask) {
  int rb = blockIdx.y, cb = blockIdx.x;
  if (cb < rb) return;
  int r = rb * 64 + threadIdx.x;
  __shared__ float4 cbox[64];
  cbox[threadIdx.x] = boxes[cb * 64 + threadIdx.x];
  __syncthreads();
  float4 bi = boxes[r];
  float areaA = fmaxf(bi.z - bi.x, 0.0f) * fmaxf(bi.w - bi.y, 0.0f);
  u64 bits = 0ull;
#pragma unroll 8
  for (int c = 0; c < 64; ++c) {
    int j = cb * 64 + c;
    float4 bj = cbox[c];
    float areaB = fmaxf(bj.z - bj.x, 0.0f) * fmaxf(bj.w - bj.y, 0.0f);
    float lxv = fmaxf(bi.x, bj.x), lyv = fmaxf(bi.y, bj.y);
    float rxv = fminf(bi.z, bj.z), ryv = fminf(bi.w, bj.w);
    float iw = fmaxf(rxv - lxv, 0.0f), ih = fmaxf(ryv - lyv, 0.0f);
    float inter = iw * ih;
    float u = areaA + areaB - inter + 1e-8f;
    float sA = inter * 33554432.0f;   // a * 2^25, exact
    float sB = u * 16777216.0f;       // u * 2^24, exact
    bool sup = ((sA - sB) - u > 0.0f);
    if (j > r && sup) bits |= (1ull << c);
  }
  mask[(size_t)r * 128 + cb] = bits;
}

// ---------------- K4: serial greedy scan ----------------
// own0/own1: full 8192-bit remv in registers (lane owns words 2l,2l+1).
// Per panel: rv[0..7] = the 8 panel words REPLICATED per lane (word advance is a
// register move); cur = current word with consumed bits set (find = ffsll(~cur)).
// Per keep: 1 dependent ds_read_b64 (cur) + 4 broadcast ds_read_b128 (rv) +
// async global_load_lds of the full 1KB row into a staging area (latency hides
// under subsequent keeps); panel-exit fold = <=16 LDS b128 reads + ORs.
__global__ __launch_bounds__(64) void nms_scan_kernel(
    const u64* __restrict__ mask, int* __restrict__ kept, int* __restrict__ num_kept) {
  __shared__ u64 slab[2][PANW * 8];  // 2 x 32 KiB double-buffered diagonal slabs
  __shared__ u64 stage[16 * 128];    // 16 KiB staged full rows (fold input)
  int lane = threadIdx.x;
  u64 own0 = 0ull, own1 = 0ull;
  int cnt = 0;

  const char* mbytes = (const char*)mask;

  // issue slab copy for panel 0: rows [0,512) x words [0,8)
#pragma unroll
  for (int it = 0; it < 32; ++it) {
    const char* g = mbytes + (size_t)(it * 16 + (lane >> 2)) * 1024 + (lane & 3) * 16;
    __builtin_amdgcn_global_load_lds(
        (const __attribute__((address_space(1))) unsigned int*)g,
        (__attribute__((address_space(3))) unsigned int*)(&slab[0][0] + it * 128), 16, 0, 0);
  }

  for (int p = 0; p < NPANEL; ++p) {
    int base = p * PANW;
    const u64* sl = &slab[p & 1][0];
    __syncthreads();  // drain slab copy for panel p

    // prefetch slab for panel p+1 NOW — overlaps this panel's scan + fold
    if (p < NPANEL - 1) {
      u64* dst = &slab[(p + 1) & 1][0];
      const char* srcBase = mbytes + (size_t)(base + PANW) * 1024 + (size_t)(p + 1) * 64;
#pragma unroll
      for (int it = 0; it < 32; ++it) {
        const char* g = srcBase + (size_t)(it * 16 + (lane >> 2)) * 1024 + (lane & 3) * 16;
        __builtin_amdgcn_global_load_lds(
            (const __attribute__((address_space(1))) unsigned int*)g,
            (__attribute__((address_space(3))) unsigned int*)(dst + it * 128), 16, 0, 0);
      }
    }

    // panel entry: replicate remv words 8p..8p+7 into rv[] on every lane
    u64 rv[8];
#pragma unroll
    for (int k = 0; k < 8; ++k) {
      u64 t = (k & 1) ? own1 : own0;
      rv[k] = __shfl(t, 4 * p + (k >> 1));
    }
    int w = 0;
    u64 cur = rv[0];
    int staged = 0;

    // serial in-panel scan
    while (cnt < PAD) {
      u64 inv = ~cur;
      if (inv == 0ull) {            // word exhausted
        if (++w == 8) break;
        cur = rv[w];                // register move — no shfl
        continue;
      }
      int bpos = __ffsll(inv) - 1;
      int li = (w << 6) + bpos;
      int gi = base + li;
      if (lane == 0) kept[cnt] = gi;
      cnt++;
      if (cnt >= PAD) break;
      cur |= (1ull << bpos);        // consume

      // stage the kept row's full 1KB for the fold (async, off critical path)
      if (staged == 16) {           // staging full: flush
        __syncthreads();
        for (int t = 0; t < 16; ++t) {
          ulonglong2 v = ((const ulonglong2*)(stage + t * 128))[lane];
          own0 |= v.x;
          own1 |= v.y;
        }
        staged = 0;
      }
      {
        const char* g = mbytes + (size_t)gi * 1024 + lane * 16;
        __builtin_amdgcn_global_load_lds(
            (const __attribute__((address_space(1))) unsigned int*)g,
            (__attribute__((address_space(3))) unsigned int*)(stage + staged * 128), 16, 0, 0);
        staged++;
      }

      // dependent hop: current word, plus replicated rv updates (broadcast reads)
      const u64* srow = sl + li * 8;
      cur |= srow[w];
      ulonglong2 s0 = ((const ulonglong2*)srow)[0];
      ulonglong2 s1 = ((const ulonglong2*)srow)[1];
      ulonglong2 s2 = ((const ulonglong2*)srow)[2];
      ulonglong2 s3 = ((const ulonglong2*)srow)[3];
      rv[0] |= s0.x; rv[1] |= s0.y;
      rv[2] |= s1.x; rv[3] |= s1.y;
      rv[4] |= s2.x; rv[5] |= s2.y;
      rv[6] |= s3.x; rv[7] |= s3.y;
    }
    if (cnt >= PAD || p == NPANEL - 1) break;

    // panel-exit fold: OR staged rows into owned remv words
    __syncthreads();  // drain staged loads (p+1 slab copy likely long done too)
    for (int t = 0; t < staged; ++t) {
      ulonglong2 v = ((const ulonglong2*)(stage + t * 128))[lane];
      own0 |= v.x;
      own1 |= v.y;
    }
  }
  if (lane == 0) *num_kept = cnt;
}

// ---------------- K5: gather outputs ----------------
__global__ __launch_bounds__(128) void gather_kernel(
    const int* __restrict__ kept, const int* __restrict__ num_kept_p,
    const int* __restrict__ sortedIdx, const float4* __restrict__ sortedBoxes,
    const float* __restrict__ scores, float* __restrict__ out) {
  int r = blockIdx.x;  // 0..299
  int t = threadIdx.x;
  float* boxes_out = out;             // (300,4)
  float* scores_out = out + PAD * 4;  // (300,81)
  int nk = *num_kept_p;
  bool valid = r < nk;
  int pos = valid ? kept[r] : 0;
  if (t < NCLS) {
    int orig = sortedIdx[pos];
    scores_out[(size_t)r * NCLS + t] = valid ? scores[(size_t)orig * NCLS + t] : 0.0f;
  }
  if (t == 96) {
    float4 b = sortedBoxes[pos];
    if (!valid) b = make_float4(0.f, 0.f, 0.f, 0.f);
    ((float4*)boxes_out)[r] = b;
  }
}

extern "C" void kernel_launch(void* const* d_in, const int* in_sizes, int n_in,
                              void* d_out, int out_size, void* d_ws, size_t ws_size,
                              hipStream_t stream) {
  const float* meta = (const float*)d_in[0];
  const float* deltas = (const float*)d_in[1];
  const float* proposals = (const float*)d_in[2];
  const float* scores = (const float*)d_in[3];
  float* out = (float*)d_out;
  char* ws = (char*)d_ws;

  float4* sel = (float4*)(ws + 0);               // 131072 B
  u64* keys = (u64*)(ws + 131072);               // 65536 B
  int* rank = (int*)(ws + 196608);               // 32768 B
  int* sortedIdx = (int*)(ws + 229376);          // 32768 B
  float4* sortedBoxes = (float4*)(ws + 262144);  // 131072 B
  int* kept = (int*)(ws + 393216);               // 1200 B
  int* num_kept = (int*)(ws + 395264);           // 4 B
  u64* mask = (u64*)(ws + 409600);               // 8 MiB row-major

  decode_kernel<<<N / 64, 64, 0, stream>>>(meta, deltas, proposals, scores, sel, keys, rank);
  rank_kernel<<<dim3(N / 256, JSPLIT), 256, 0, stream>>>(keys, rank);
  scatter_kernel<<<N / 256, 256, 0, stream>>>(rank, sel, sortedIdx, sortedBoxes);
  mask_kernel<<<dim3(N / 64, N / 64), 64, 0, stream>>>(sortedBoxes, mask);
  nms_scan_kernel<<<1, 64, 0, stream>>>(mask, kept, num_kept);
  gather_kernel<<<PAD, 128, 0, stream>>>(kept, num_kept, sortedIdx, sortedBoxes, scores, out);
}

// Round 7
// 135.912 us; speedup vs baseline: 1.7055x; 1.7055x over previous
//
#include <hip/hip_runtime.h>

#define N 8192
#define NCLS 81
#define PAD 300
#define NPANEL 16
#define PANW 512
#define JSPLIT 8

typedef unsigned long long u64;

// ---------------- K1: decode + argmax pick + key pack + rank zero ----------------
__global__ __launch_bounds__(64) void decode_kernel(
    const float* __restrict__ meta, const float* __restrict__ deltas,
    const float* __restrict__ proposals, const float* __restrict__ scores,
    float4* __restrict__ sel, u64* __restrict__ keys, int* __restrict__ rank) {
  int row = blockIdx.x * 64 + threadIdx.x;
  if (row >= N) return;
  float H = meta[0], W = meta[1], sc = meta[2];
  const float* p = proposals + row * 4;
  float x1 = p[0] / sc, y1 = p[1] / sc, x2 = p[2] / sc, y2 = p[3] / sc;
  float w = x2 - x1 + 1.0f, h = y2 - y1 + 1.0f;
  float cx = x1 + 0.5f * w, cy = y1 + 0.5f * h;

  const float* s = scores + (size_t)row * NCLS;
  int best = 0;
  float bs = s[0];
  float ms = -1e30f;  // max over classes 1..80
  for (int c = 1; c < NCLS; ++c) {
    float v = s[c];
    if (v > bs) { bs = v; best = c; }  // strict > : first-max, matches jnp.argmax
    ms = fmaxf(ms, v);
  }

  const float* d = deltas + (size_t)row * (4 * NCLS) + best * 4;
  float pcx = d[0] * w + cx;
  float pcy = d[1] * h + cy;
  float pw = expf(d[2]) * w;
  float ph = expf(d[3]) * h;
  float lx = W - 1.0f, ly = H - 1.0f;
  float ox1 = fminf(fmaxf(pcx - 0.5f * pw, 0.0f), lx);
  float oy1 = fminf(fmaxf(pcy - 0.5f * ph, 0.0f), ly);
  float ox2 = fminf(fmaxf(pcx + 0.5f * pw, 0.0f), lx);
  float oy2 = fminf(fmaxf(pcy + 0.5f * ph, 0.0f), ly);
  sel[row] = make_float4(ox1, oy1, ox2, oy2);
  keys[row] = ((u64)(~__float_as_uint(ms)) << 32) | (unsigned int)row;
  rank[row] = 0;
}

// ---------------- K2a: brute-force rank (stable sort of unique keys) ----------------
__global__ __launch_bounds__(256) void rank_kernel(
    const u64* __restrict__ keys, int* __restrict__ rank) {
  int i = blockIdx.x * 256 + threadIdx.x;
  u64 ki = keys[i];
  int j0 = blockIdx.y * (N / JSPLIT);
  int c = 0;
#pragma unroll 8
  for (int j = j0; j < j0 + N / JSPLIT; ++j) c += (keys[j] < ki);
  atomicAdd(&rank[i], c);
}

// ---------------- K2b: scatter into sorted order ----------------
__global__ __launch_bounds__(256) void scatter_kernel(
    const int* __restrict__ rank, const float4* __restrict__ sel,
    int* __restrict__ sortedIdx, float4* __restrict__ sortedBoxes) {
  int i = blockIdx.x * 256 + threadIdx.x;
  int r = rank[i];
  sortedIdx[r] = i;
  sortedBoxes[r] = sel[i];
}

// ---------------- K3: suppression bitmask, ROW-MAJOR, upper triangle only ------
// mask[r*128 + cb] bit c set iff j = cb*64+c, j > r, IoU > 0.5.
// Lower-tri words left as poison: scan's full-row b128 reads pull poison only
// into rv words < current word (never re-read); fold poison lands at words
// < 8(p+1), entries read words >= 8(p+1). Division removed bit-exactly:
// RN(a/u) > 0.5  <=>  a*2^25 - u*2^24 - u > 0.
__global__ __launch_bounds__(64) void mask_kernel(
    const float4* __restrict__ boxes, u64* __restrict__ mask) {
  int rb = blockIdx.y, cb = blockIdx.x;
  if (cb < rb) return;
  int r = rb * 64 + threadIdx.x;
  __shared__ float4 cbox[64];
  cbox[threadIdx.x] = boxes[cb * 64 + threadIdx.x];
  __syncthreads();
  float4 bi = boxes[r];
  float areaA = fmaxf(bi.z - bi.x, 0.0f) * fmaxf(bi.w - bi.y, 0.0f);
  u64 bits = 0ull;
#pragma unroll 8
  for (int c = 0; c < 64; ++c) {
    int j = cb * 64 + c;
    float4 bj = cbox[c];
    float areaB = fmaxf(bj.z - bj.x, 0.0f) * fmaxf(bj.w - bj.y, 0.0f);
    float lxv = fmaxf(bi.x, bj.x), lyv = fmaxf(bi.y, bj.y);
    float rxv = fminf(bi.z, bj.z), ryv = fminf(bi.w, bj.w);
    float iw = fmaxf(rxv - lxv, 0.0f), ih = fmaxf(ryv - lyv, 0.0f);
    float inter = iw * ih;
    float u = areaA + areaB - inter + 1e-8f;
    float sA = inter * 33554432.0f;  // * 2^25, exact
    float sB = u * 16777216.0f;      // * 2^24, exact
    bool sup = ((sA - sB) - u > 0.0f);
    if (j > r && sup) bits |= (1ull << c);
  }
  mask[(size_t)r * 128 + cb] = bits;
}

// ---------------- K4: serial greedy scan ----------------
// R4 structure (no VM ops inside the scan loop — R5's vmcnt-hazard lesson) plus:
// (a) panel words in named regs rv0..rv7 (advance = cndmask chain, no shfl);
// (b) 2-way speculative keeps (both rows loaded in one LDS latency, resolved
//     by one bit test — Pr[fail] ~ row density ~0.3%).
__global__ __launch_bounds__(64) void nms_scan_kernel(
    const u64* __restrict__ mask, int* __restrict__ kept, int* __restrict__ num_kept) {
  __shared__ u64 slab[2][PANW * 8];  // 2 x 32 KiB double-buffered diagonal slabs
  __shared__ int keptLi[PAD];        // in-panel indices, indexed by global cnt
  int lane = threadIdx.x;
  u64 own0 = 0ull, own1 = 0ull;      // lane owns global remv words 2l, 2l+1
  int cnt = 0;
  const char* mb = (const char*)mask;

  // slab copy for panel 0: rows [0,512) x words [0,8) (64B per row, 16 rows/issue)
#pragma unroll
  for (int it = 0; it < 32; ++it) {
    const char* g = mb + (size_t)(it * 16 + (lane >> 2)) * 1024 + (lane & 3) * 16;
    __builtin_amdgcn_global_load_lds(
        (const __attribute__((address_space(1))) unsigned int*)g,
        (__attribute__((address_space(3))) unsigned int*)(&slab[0][0] + it * 128), 16, 0, 0);
  }

  for (int p = 0; p < NPANEL; ++p) {
    int base = p * PANW;
    const u64* sl = &slab[p & 1][0];
    __syncthreads();  // drains slab copy (vmcnt0) — no VM ops live during scan

    // panel entry: replicate remv words 8p..8p+7 into named regs
    u64 rv0 = __shfl(own0, 4 * p), rv1 = __shfl(own1, 4 * p);
    u64 rv2 = __shfl(own0, 4 * p + 1), rv3 = __shfl(own1, 4 * p + 1);
    u64 rv4 = __shfl(own0, 4 * p + 2), rv5 = __shfl(own1, 4 * p + 2);
    u64 rv6 = __shfl(own0, 4 * p + 3), rv7 = __shfl(own1, 4 * p + 3);
    int w = 0;
    u64 cur = rv0;
    int panelFirst = cnt;

    while (cnt < PAD) {
      u64 inv = ~cur;
      if (inv == 0ull) {  // word exhausted
        if (++w == 8) break;
        cur = (w == 1) ? rv1 : (w == 2) ? rv2 : (w == 3) ? rv3 : (w == 4) ? rv4
            : (w == 5) ? rv5 : (w == 6) ? rv6 : rv7;
        continue;
      }
      int b1 = __ffsll(inv) - 1;
      u64 inv2 = inv & (inv - 1);
      int li1 = (w << 6) + b1;
      int b2 = inv2 ? (__ffsll(inv2) - 1) : -1;
      int li2 = inv2 ? ((w << 6) + b2) : li1;
      const u64* rA = sl + li1 * 8;
      const u64* rB = sl + li2 * 8;
      u64 mA = rA[w];  // dependent hop (chain)
      u64 mB = rB[w];  // speculative, same latency window
      ulonglong2 a0 = ((const ulonglong2*)rA)[0], a1 = ((const ulonglong2*)rA)[1];
      ulonglong2 a2 = ((const ulonglong2*)rA)[2], a3 = ((const ulonglong2*)rA)[3];
      if (lane == 0) kept[cnt] = base + li1;
      keptLi[cnt] = li1;
      cnt++;
      cur |= mA | (1ull << b1);
      rv0 |= a0.x; rv1 |= a0.y; rv2 |= a1.x; rv3 |= a1.y;
      rv4 |= a2.x; rv5 |= a2.y; rv6 |= a3.x; rv7 |= a3.y;
      if (b2 >= 0 && cnt < PAD && !((mA >> b2) & 1ull)) {  // speculation success
        ulonglong2 c0 = ((const ulonglong2*)rB)[0], c1 = ((const ulonglong2*)rB)[1];
        ulonglong2 c2 = ((const ulonglong2*)rB)[2], c3 = ((const ulonglong2*)rB)[3];
        if (lane == 0) kept[cnt] = base + li2;
        keptLi[cnt] = li2;
        cnt++;
        cur |= mB | (1ull << b2);
        rv0 |= c0.x; rv1 |= c0.y; rv2 |= c1.x; rv3 |= c1.y;
        rv4 |= c2.x; rv5 |= c2.y; rv6 |= c3.x; rv7 |= c3.y;
      }
    }
    if (cnt >= PAD || p == NPANEL - 1) break;

    // issue slab copy for panel p+1 (overlaps the fold below; drained at top barrier)
    {
      u64* dst = &slab[(p + 1) & 1][0];
      const char* srcB = mb + (size_t)(base + PANW) * 1024 + (size_t)(p + 1) * 64;
#pragma unroll
      for (int it = 0; it < 32; ++it) {
        const char* g = srcB + (size_t)(it * 16 + (lane >> 2)) * 1024 + (lane & 3) * 16;
        __builtin_amdgcn_global_load_lds(
            (const __attribute__((address_space(1))) unsigned int*)g,
            (__attribute__((address_space(3))) unsigned int*)(dst + it * 128), 16, 0, 0);
      }
    }

    // panel-exit fold: OR this panel's keeps' FULL 1KB rows into owned words.
    // Row-major: lane reads 16B at row + lane*16 == words 2l, 2l+1. 8-batched ILP.
    int nk = cnt - panelFirst;
    for (int t0 = 0; t0 < nk; t0 += 8) {
      int m = nk - t0;
      ulonglong2 v0, v1, v2, v3, v4, v5, v6, v7;
#define ROWP(t) (((const ulonglong2*)(mask + (size_t)(base + keptLi[panelFirst + (t)]) * 128))[lane])
      if (0 < m) v0 = ROWP(t0 + 0);
      if (1 < m) v1 = ROWP(t0 + 1);
      if (2 < m) v2 = ROWP(t0 + 2);
      if (3 < m) v3 = ROWP(t0 + 3);
      if (4 < m) v4 = ROWP(t0 + 4);
      if (5 < m) v5 = ROWP(t0 + 5);
      if (6 < m) v6 = ROWP(t0 + 6);
      if (7 < m) v7 = ROWP(t0 + 7);
#undef ROWP
      if (0 < m) { own0 |= v0.x; own1 |= v0.y; }
      if (1 < m) { own0 |= v1.x; own1 |= v1.y; }
      if (2 < m) { own0 |= v2.x; own1 |= v2.y; }
      if (3 < m) { own0 |= v3.x; own1 |= v3.y; }
      if (4 < m) { own0 |= v4.x; own1 |= v4.y; }
      if (5 < m) { own0 |= v5.x; own1 |= v5.y; }
      if (6 < m) { own0 |= v6.x; own1 |= v6.y; }
      if (7 < m) { own0 |= v7.x; own1 |= v7.y; }
    }
  }
  if (lane == 0) *num_kept = cnt;
}

// ---------------- K5: gather outputs ----------------
__global__ __launch_bounds__(128) void gather_kernel(
    const int* __restrict__ kept, const int* __restrict__ num_kept_p,
    const int* __restrict__ sortedIdx, const float4* __restrict__ sortedBoxes,
    const float* __restrict__ scores, float* __restrict__ out) {
  int r = blockIdx.x;  // 0..299
  int t = threadIdx.x;
  float* boxes_out = out;             // (300,4)
  float* scores_out = out + PAD * 4;  // (300,81)
  int nk = *num_kept_p;
  bool valid = r < nk;
  int pos = valid ? kept[r] : 0;
  if (t < NCLS) {
    int orig = sortedIdx[pos];
    scores_out[(size_t)r * NCLS + t] = valid ? scores[(size_t)orig * NCLS + t] : 0.0f;
  }
  if (t == 96) {
    float4 b = sortedBoxes[pos];
    if (!valid) b = make_float4(0.f, 0.f, 0.f, 0.f);
    ((float4*)boxes_out)[r] = b;
  }
}

extern "C" void kernel_launch(void* const* d_in, const int* in_sizes, int n_in,
                              void* d_out, int out_size, void* d_ws, size_t ws_size,
                              hipStream_t stream) {
  const float* meta = (const float*)d_in[0];
  const float* deltas = (const float*)d_in[1];
  const float* proposals = (const float*)d_in[2];
  const float* scores = (const float*)d_in[3];
  float* out = (float*)d_out;
  char* ws = (char*)d_ws;

  float4* sel = (float4*)(ws + 0);               // 131072 B
  u64* keys = (u64*)(ws + 131072);               // 65536 B
  int* rank = (int*)(ws + 196608);               // 32768 B
  int* sortedIdx = (int*)(ws + 229376);          // 32768 B
  float4* sortedBoxes = (float4*)(ws + 262144);  // 131072 B
  int* kept = (int*)(ws + 393216);               // 1200 B
  int* num_kept = (int*)(ws + 395264);           // 4 B
  u64* mask = (u64*)(ws + 409600);               // 8 MiB row-major

  decode_kernel<<<N / 64, 64, 0, stream>>>(meta, deltas, proposals, scores, sel, keys, rank);
  rank_kernel<<<dim3(N / 256, JSPLIT), 256, 0, stream>>>(keys, rank);
  scatter_kernel<<<N / 256, 256, 0, stream>>>(rank, sel, sortedIdx, sortedBoxes);
  mask_kernel<<<dim3(N / 64, N / 64), 64, 0, stream>>>(sortedBoxes, mask);
  nms_scan_kernel<<<1, 64, 0, stream>>>(mask, kept, num_kept);
  gather_kernel<<<PAD, 128, 0, stream>>>(kept, num_kept, sortedIdx, sortedBoxes, scores, out);
}